// Round 15
// baseline (340.445 us; speedup 1.0000x reference)
//
#include <hip/hip_runtime.h>

typedef short short8 __attribute__((ext_vector_type(8)));
typedef float float4v __attribute__((ext_vector_type(4)));
typedef unsigned short u16;
typedef unsigned int u32;

#define T_LEN 4096
#define DDIM 512
#define BATCH 8
#define MROWS 32768
#define CH 32
#define NC 128   // T_LEN / CH

__device__ __forceinline__ u16 f2b(float x) {
    unsigned u = __float_as_uint(x);
    unsigned r = (u + 0x7FFFu + ((u >> 16) & 1u)) >> 16;
    return (u16)r;
}
__device__ __forceinline__ float b2f(u16 h) {
    return __uint_as_float((u32)h << 16);
}
__device__ __forceinline__ float sigm(float x) {
    return __builtin_amdgcn_rcpf(1.f + __builtin_amdgcn_exp2f(-1.44269504f * x));
}
__device__ __forceinline__ float tanh_fast(float x) {
    return 1.f - 2.f * __builtin_amdgcn_rcpf(1.f + __builtin_amdgcn_exp2f(2.88539008f * x));
}

__device__ __forceinline__ void gl2lds16(const u16* g, u16* l) {
    __builtin_amdgcn_global_load_lds(
        (const __attribute__((address_space(1))) void*)g,
        (__attribute__((address_space(3))) void*)l, 16, 0, 0);
}

// ---------------- converts ----------------
__global__ __launch_bounds__(256) void cvt_x(const float* __restrict__ x,
                                             u16* __restrict__ xb, size_t n) {
    size_t i = ((size_t)blockIdx.x * 256 + threadIdx.x) * 4;
    if (i < n) {
        float4v v = *(const float4v*)&x[i];
        ushort4 p;
        p.x = f2b(v[0]); p.y = f2b(v[1]); p.z = f2b(v[2]); p.w = f2b(v[3]);
        *(ushort4*)&xb[i] = p;
    }
}

// Wt[j][k] = W[e][k][h], j = e*512+h
__global__ __launch_bounds__(256) void cvt_wt(const float* __restrict__ W,
                                              u16* __restrict__ Wt, int N) {
    int idx = blockIdx.x * 256 + threadIdx.x;
    if (idx >= N * 512) return;
    int j = idx >> 9;
    int k = idx & 511;
    int e = j >> 9, h = j & 511;
    Wt[(size_t)j * 512 + k] = f2b(W[((size_t)e * 512 + k) * 512 + h]);
}

// ---------------- 8-phase GEMM: faithful m201 geometry, K=512 ----------
// BM=BN=256, BK=64, 8 waves (2M x 4N), wave tile 128x64, acc[8][4].
// LDS = 2 K-step buffers x (A 256x64 + B 256x64) x 2B = 128KB; buffer for
// K-step kt is lsX[kt&1]. Iteration it covers K-steps {2it, 2it+1} = 8
// phases; phase p: kt2=p>>2 (buffer), q=p&3 -> C-quadrant (mh=q>>1,nh=q&1),
// 16 MFMA each.
// Staging (burst-at-buffer-free): buf0's last read is phase 2 (af mh=1);
// after phase 2's closing barrier, phase 3 issues ALL 8 loads for buf0's
// next K-step (2it+2), then vmcnt(8) -> the PREVIOUS burst (buf1, kstep
// 2it+1) is complete before phases 4-7 read it. Symmetric at phase 7
// (buf1 <- kstep 2it+3, vmcnt(8) validates buf0's burst). Loads thus
// always have ~4 phases of cover and never drain mid-loop. Last iter:
// vmcnt(0) at phase 3, no wait at phase 7.
// Swizzle: rows are 128B; chunk c' = c ^ (r&7). Reads: per quarter-wave
// each chunk position hit by 2 lanes -> 2-way (free, m136). Staging source
// permutes chunks WITHIN a row's 128B -> coalesced; LDS dest linear.
// Visibility: vmcnt-before-barrier => stages visible to all waves after
// the barrier; ds_reads waited by lgkmcnt(0) before each phase's MFMA,
// so all reads of a buffer complete before the barrier that precedes its
// re-staging.
template <int MODE>
__global__ __launch_bounds__(512, 2) void gemm_act(
    const u16* __restrict__ A, const u16* __restrict__ Bt,
    const float* __restrict__ bias, void* __restrict__ o0v,
    void* __restrict__ o1v, void* __restrict__ o2v, void* __restrict__ o3v) {
    constexpr int K = 512;
    constexpr int GXX = (MODE == 1) ? 4 : (MODE == 2) ? 8 : 2;  // N/256
    constexpr int NWG = 128 * GXX;
    __shared__ u16 lsA[2][256 * 64];   // 64KB
    __shared__ u16 lsB[2][256 * 64];   // 64KB
    const int tid = threadIdx.x;
    const int lane = tid & 63;
    const int wid = tid >> 6;          // 0..7
    const int wr = wid >> 2;           // 0..1 (M: 128-row half)
    const int wc = wid & 3;            // 0..3 (N: 64-col quarter)
    const int l0 = lane & 15, lh = lane >> 4;

    // chunked XCD swizzle (bijective: NWG % 8 == 0)
    const int h = blockIdx.x;
    const int l = (h & 7) * (NWG / 8) + (h >> 3);
    const int bn0 = (l & (GXX - 1)) * 256;
    const int bm0 = (l / GXX) * 256;

    float4v acc[8][4];
#pragma unroll
    for (int m = 0; m < 8; ++m)
#pragma unroll
        for (int n = 0; n < 4; ++n) acc[m][n] = (float4v){0.f, 0.f, 0.f, 0.f};

    // staging geometry: half-tile = 128 rows x 64 k = 512 thr x 2 x 16B
    // flat = i*512+tid: row = flat>>3 (0..127), slot = flat&7,
    // source chunk = slot ^ (row&7) (within row's 128B span -> coalesced)
    int sr[2], sc[2];
#pragma unroll
    for (int i = 0; i < 2; ++i) {
        int flat = i * 512 + tid;
        sr[i] = flat >> 3;
        sc[i] = ((flat & 7) ^ (sr[i] & 7)) * 8;
    }

    // stage one full K-step (A both halves + B both halves = 8 loads/thread)
#define STAGE8(buf, ktile)                                                    \
    {                                                                         \
        const int ko = (ktile) * 64;                                          \
        _Pragma("unroll") for (int i = 0; i < 2; ++i) {                       \
            gl2lds16(&A[(size_t)(bm0 + sr[i]) * K + ko + sc[i]],              \
                     &lsA[buf][(i * 512 + tid) * 8]);                         \
            gl2lds16(&A[(size_t)(bm0 + 128 + sr[i]) * K + ko + sc[i]],        \
                     &lsA[buf][8192 + (i * 512 + tid) * 8]);                  \
            gl2lds16(&Bt[(size_t)(bn0 + sr[i]) * K + ko + sc[i]],             \
                     &lsB[buf][(i * 512 + tid) * 8]);                         \
            gl2lds16(&Bt[(size_t)(bn0 + 128 + sr[i]) * K + ko + sc[i]],       \
                     &lsB[buf][8192 + (i * 512 + tid) * 8]);                  \
        }                                                                     \
    }

    short8 af[4][2];     // A frags for current (kt2, mh): 4 m x 2 k-slices
    short8 bf[2][2][2];  // B frags [nh][ni][kk], both nh live

    // prologue: K-steps 0,1 into bufs 0,1; validate buf0
    STAGE8(0, 0);
    STAGE8(1, 1);
    asm volatile("s_waitcnt vmcnt(8)" ::: "memory");
    __builtin_amdgcn_s_barrier();

#define PHASE(p_)                                                             \
    {                                                                         \
        constexpr int kt2_ = (p_) >> 2, q_ = (p_) & 3;                        \
        constexpr int mh_ = q_ >> 1, nh_ = q_ & 1;                            \
        if (q_ == 0 || q_ == 2) {                                             \
            _Pragma("unroll") for (int mi = 0; mi < 4; ++mi)                  \
                _Pragma("unroll") for (int kk = 0; kk < 2; ++kk) {            \
                    int r = wr * 128 + mh_ * 64 + mi * 16 + l0;               \
                    af[mi][kk] = *(const short8*)&lsA[kt2_][                  \
                        r * 64 + (((kk * 4 + lh) ^ (r & 7)) * 8)];            \
                }                                                             \
        }                                                                     \
        if (q_ == 0 || q_ == 1) {                                             \
            _Pragma("unroll") for (int ni = 0; ni < 2; ++ni)                  \
                _Pragma("unroll") for (int kk = 0; kk < 2; ++kk) {            \
                    int r = wc * 64 + nh_ * 32 + ni * 16 + l0;                \
                    bf[nh_][ni][kk] = *(const short8*)&lsB[kt2_][             \
                        r * 64 + (((kk * 4 + lh) ^ (r & 7)) * 8)];            \
                }                                                             \
        }                                                                     \
        if (p_ == 3) {                                                        \
            if (it < 3) {                                                     \
                STAGE8(0, 2 * it + 2);                                        \
                asm volatile("s_waitcnt vmcnt(8)" ::: "memory");              \
            } else {                                                          \
                asm volatile("s_waitcnt vmcnt(0)" ::: "memory");              \
            }                                                                 \
        }                                                                     \
        if (p_ == 7) {                                                        \
            if (it < 3) {                                                     \
                STAGE8(1, 2 * it + 3);                                        \
                asm volatile("s_waitcnt vmcnt(8)" ::: "memory");              \
            }                                                                 \
        }                                                                     \
        __builtin_amdgcn_s_barrier();                                         \
        asm volatile("s_waitcnt lgkmcnt(0)" ::: "memory");                    \
        __builtin_amdgcn_sched_barrier(0);                                    \
        __builtin_amdgcn_s_setprio(1);                                        \
        _Pragma("unroll") for (int kk = 0; kk < 2; ++kk)                      \
            _Pragma("unroll") for (int mi = 0; mi < 4; ++mi)                  \
                _Pragma("unroll") for (int ni = 0; ni < 2; ++ni)              \
                    acc[mh_ * 4 + mi][nh_ * 2 + ni] =                         \
                        __builtin_amdgcn_mfma_f32_16x16x32_bf16(              \
                            af[mi][kk], bf[nh_][ni][kk],                      \
                            acc[mh_ * 4 + mi][nh_ * 2 + ni], 0, 0, 0);        \
        __builtin_amdgcn_s_setprio(0);                                        \
        __builtin_amdgcn_s_barrier();                                         \
    }

    for (int it = 0; it < 4; ++it) {
        PHASE(0) PHASE(1) PHASE(2) PHASE(3)
        PHASE(4) PHASE(5) PHASE(6) PHASE(7)
    }
#undef PHASE
#undef STAGE8

#pragma unroll
    for (int m = 0; m < 8; ++m) {
#pragma unroll
        for (int n = 0; n < 4; ++n) {
            int col = bn0 + wc * 64 + n * 16 + l0;
            float bv = bias[col];
#pragma unroll
            for (int r = 0; r < 4; ++r) {
                int rw = bm0 + wr * 128 + m * 16 + lh * 4 + r;
                float u = acc[m][n][r] + bv;
                size_t oidx = (size_t)rw * 512 + (col & 511);
                if (MODE == 1) {
                    if (col < 512)
                        ((u16*)o0v)[oidx] = f2b(tanh_fast(u));
                    else
                        ((u16*)o1v)[oidx] = f2b(sigm(u));
                } else if (MODE == 2) {
                    int e = col >> 9;
                    if (e == 0)
                        ((u16*)o0v)[oidx] = f2b(sigm(u));
                    else if (e == 1)
                        ((u16*)o1v)[oidx] = f2b(sigm(u));
                    else if (e == 2)
                        ((u16*)o2v)[oidx] = f2b(sigm(u));
                    else
                        ((u16*)o3v)[oidx] = f2b(tanh_fast(u));
                } else {
                    ((float*)o0v)[oidx] = u;
                }
            }
        }
    }
}

// ---------------- chunked scan (bf16 streams, f32 state; R12 form) ------
template <int S>
__global__ __launch_bounds__(128) void scan_p1(const u16* __restrict__ f,
                                               const u16* __restrict__ v,
                                               const u16* __restrict__ z,
                                               float* __restrict__ cA,
                                               float* __restrict__ cB) {
    int d0 = threadIdx.x * 4;
    int c = blockIdx.x & (NC - 1);
    int b = blockIdx.x >> 7;
    size_t base = ((size_t)b * T_LEN + c * CH) * DDIM + d0;
    float Aa[4] = {1.f, 1.f, 1.f, 1.f}, Bb[4] = {0.f, 0.f, 0.f, 0.f};
    for (int t = 0; t < CH; ++t) {
        ushort4 fq = *(const ushort4*)&f[base];
        ushort4 vq = *(const ushort4*)&v[base];
        float ff[4] = {b2f(fq.x), b2f(fq.y), b2f(fq.z), b2f(fq.w)};
        float gg[4] = {b2f(vq.x), b2f(vq.y), b2f(vq.z), b2f(vq.w)};
        if (S == 2) {
            ushort4 zq = *(const ushort4*)&z[base];
            gg[0] *= b2f(zq.x); gg[1] *= b2f(zq.y);
            gg[2] *= b2f(zq.z); gg[3] *= b2f(zq.w);
        }
#pragma unroll
        for (int j = 0; j < 4; ++j) {
            float g = (1.f - ff[j]) * gg[j];
            Bb[j] = ff[j] * Bb[j] + g;
            Aa[j] *= ff[j];
        }
        base += DDIM;
    }
    size_t ci = (size_t)c * 4096 + b * DDIM + d0;
#pragma unroll
    for (int j = 0; j < 4; ++j) {
        cA[ci + j] = Aa[j];
        cB[ci + j] = Bb[j];
    }
}

__global__ __launch_bounds__(256) void scan_p2(float* __restrict__ cA,
                                               const float* __restrict__ cB) {
    int ln = blockIdx.x * 256 + threadIdx.x;  // 0..4095 = b*512+d
    float h = 0.f;
    for (int c = 0; c < NC; ++c) {
        size_t ix = (size_t)c * 4096 + ln;
        float a = cA[ix], bb = cB[ix];
        cA[ix] = h;  // exclusive carry-in
        h = a * h + bb;
    }
}

template <int S>
__global__ __launch_bounds__(128) void scan_p3(
    const u16* __restrict__ f, const u16* __restrict__ v,
    const u16* __restrict__ z, const u16* __restrict__ o,
    const float* __restrict__ cA, u16* __restrict__ hb,
    float* __restrict__ hid) {
    int d0 = threadIdx.x * 4;
    int c = blockIdx.x & (NC - 1);
    int b = blockIdx.x >> 7;
    size_t base = ((size_t)b * T_LEN + c * CH) * DDIM + d0;
    size_t ci = (size_t)c * 4096 + b * DDIM + d0;
    float h[4] = {cA[ci], cA[ci + 1], cA[ci + 2], cA[ci + 3]};
    for (int t = 0; t < CH; ++t) {
        ushort4 fq = *(const ushort4*)&f[base];
        ushort4 vq = *(const ushort4*)&v[base];
        float ff[4] = {b2f(fq.x), b2f(fq.y), b2f(fq.z), b2f(fq.w)};
        float gg[4] = {b2f(vq.x), b2f(vq.y), b2f(vq.z), b2f(vq.w)};
        if (S == 2) {
            ushort4 zq = *(const ushort4*)&z[base];
            gg[0] *= b2f(zq.x); gg[1] *= b2f(zq.y);
            gg[2] *= b2f(zq.z); gg[3] *= b2f(zq.w);
        }
        float w[4];
#pragma unroll
        for (int j = 0; j < 4; ++j) {
            float g = (1.f - ff[j]) * gg[j];
            h[j] = ff[j] * h[j] + g;
            w[j] = h[j];
        }
        if (S == 2) {
            ushort4 oq = *(const ushort4*)&o[base];
            w[0] *= b2f(oq.x); w[1] *= b2f(oq.y);
            w[2] *= b2f(oq.z); w[3] *= b2f(oq.w);
        }
        ushort4 p;
        p.x = f2b(w[0]); p.y = f2b(w[1]); p.z = f2b(w[2]); p.w = f2b(w[3]);
        *(ushort4*)&hb[base] = p;
        base += DDIM;
    }
    if (c == NC - 1) {
#pragma unroll
        for (int j = 0; j < 4; ++j)
            hid[b * 1024 + (S == 1 ? 0 : 512) + d0 + j] = h[j];
    }
}

// ---------------- launch ----------------
extern "C" void kernel_launch(void* const* d_in, const int* in_sizes, int n_in,
                              void* d_out, int out_size, void* d_ws,
                              size_t ws_size, hipStream_t stream) {
    const float* x = (const float*)d_in[0];
    const float* W_in = (const float*)d_in[1];
    const float* b_in = (const float*)d_in[2];
    const float* W_mid = (const float*)d_in[3];
    const float* b_mid = (const float*)d_in[4];
    const float* W_out = (const float*)d_in[5];
    const float* b_out = (const float*)d_in[6];
    float* out = (float*)d_out;
    char* ws = (char*)d_ws;

    const size_t MB = 1u << 20;
    const size_t MD = (size_t)MROWS * DDIM;  // 16.7M elems

    u16* wt_in = (u16*)(ws);              // 1 MB
    u16* wt_mid = (u16*)(ws + 1 * MB);    // 2 MB
    u16* wt_out = (u16*)(ws + 3 * MB);    // 0.5 MB
    u16* hb = (u16*)(ws + 4 * MB);        // 32 MB (xb -> h1 -> s)
    u16* S0 = (u16*)(ws + 36 * MB);       // 32 MB
    u16* S1 = (u16*)(ws + 68 * MB);       // 32 MB
    u16* S2 = (u16*)(ws + 100 * MB);      // 32 MB
    u16* S3 = (u16*)(ws + 132 * MB);      // 32 MB
    float* cA = (float*)(ws + 164 * MB);  // 2 MB
    float* cB = (float*)(ws + 166 * MB);  // 2 MB
    float* hid = out + MD;

    cvt_x<<<(int)(MD / 4 / 256), 256, 0, stream>>>(x, hb, MD);
    cvt_wt<<<(1024 * 512) / 256, 256, 0, stream>>>(W_in, wt_in, 1024);
    cvt_wt<<<(2048 * 512) / 256, 256, 0, stream>>>(W_mid, wt_mid, 2048);
    cvt_wt<<<(512 * 512) / 256, 256, 0, stream>>>(W_out, wt_out, 512);

    // GEMM1: v(S0)=tanh, f1(S1)=sigmoid   (128 Mblk x 4 Nblk = 512)
    gemm_act<1><<<512, 512, 0, stream>>>(hb, wt_in, b_in, S0, S1, nullptr,
                                         nullptr);
    // scan1: h1 = scan(f1, (1-f1)*v) -> hb bf16; hidden_pre
    scan_p1<1><<<1024, 128, 0, stream>>>(S1, S0, nullptr, cA, cB);
    scan_p2<<<16, 256, 0, stream>>>(cA, cB);
    scan_p3<1><<<1024, 128, 0, stream>>>(S1, S0, nullptr, nullptr, cA, hb, hid);

    // GEMM2: f2(S0), i(S1), o(S2), z(S3)  (128 x 8 = 1024)
    gemm_act<2><<<1024, 512, 0, stream>>>(hb, wt_mid, b_mid, S0, S1, S2, S3);
    // scan2: h2 = scan(f2, (1-f2)*i*z); s = h2*o -> hb bf16; hidden_middle
    scan_p1<2><<<1024, 128, 0, stream>>>(S0, S1, S3, cA, cB);
    scan_p2<<<16, 256, 0, stream>>>(cA, cB);
    scan_p3<2><<<1024, 128, 0, stream>>>(S0, S1, S3, S2, cA, hb, hid);

    // GEMM3: out = s@W_out + b_out (f32)  (128 x 2 = 256)
    gemm_act<3><<<256, 512, 0, stream>>>(hb, wt_out, b_out, out, nullptr,
                                         nullptr, nullptr);
}

// Round 16
// 259.713 us; speedup vs baseline: 1.3109x; 1.3109x over previous
//
#include <hip/hip_runtime.h>

typedef short short8 __attribute__((ext_vector_type(8)));
typedef float float4v __attribute__((ext_vector_type(4)));
typedef unsigned short u16;
typedef unsigned int u32;

#define T_LEN 4096
#define DDIM 512
#define BATCH 8
#define MROWS 32768
#define CH 32
#define NC 128   // T_LEN / CH

__device__ __forceinline__ u16 f2b(float x) {
    unsigned u = __float_as_uint(x);
    unsigned r = (u + 0x7FFFu + ((u >> 16) & 1u)) >> 16;
    return (u16)r;
}
__device__ __forceinline__ float b2f(u16 h) {
    return __uint_as_float((u32)h << 16);
}
__device__ __forceinline__ float sigm(float x) {
    return __builtin_amdgcn_rcpf(1.f + __builtin_amdgcn_exp2f(-1.44269504f * x));
}
__device__ __forceinline__ float tanh_fast(float x) {
    return 1.f - 2.f * __builtin_amdgcn_rcpf(1.f + __builtin_amdgcn_exp2f(2.88539008f * x));
}

__device__ __forceinline__ void gl2lds16(const u16* g, u16* l) {
    __builtin_amdgcn_global_load_lds(
        (const __attribute__((address_space(1))) void*)g,
        (__attribute__((address_space(3))) void*)l, 16, 0, 0);
}

// ---------------- converts ----------------
__global__ __launch_bounds__(256) void cvt_x(const float* __restrict__ x,
                                             u16* __restrict__ xb, size_t n) {
    size_t i = ((size_t)blockIdx.x * 256 + threadIdx.x) * 4;
    if (i < n) {
        float4v v = *(const float4v*)&x[i];
        ushort4 p;
        p.x = f2b(v[0]); p.y = f2b(v[1]); p.z = f2b(v[2]); p.w = f2b(v[3]);
        *(ushort4*)&xb[i] = p;
    }
}

// Gate-interleaved weight transpose: output row j holds (gate, d) so that
// a GEMM lane's acc[m][0..NG-1] are all NG gates of the SAME d.
// MODE 1 (N=1024, NG=2): gate=(j>>4)&1, d=(j>>5)*16+(j&15)
// MODE 2 (N=2048, NG=4): gate=(j>>4)&3, d=(j>>6)*16+(j&15)
// MODE 3 (N=512,  NG=1): gate=0, d=j
template <int MODE>
__global__ __launch_bounds__(256) void cvt_wt(const float* __restrict__ W,
                                              u16* __restrict__ Wt, int N) {
    int idx = blockIdx.x * 256 + threadIdx.x;
    if (idx >= N * 512) return;
    int j = idx >> 9;
    int k = idx & 511;
    int gate, d;
    if (MODE == 1) { gate = (j >> 4) & 1; d = (j >> 5) * 16 + (j & 15); }
    else if (MODE == 2) { gate = (j >> 4) & 3; d = (j >> 6) * 16 + (j & 15); }
    else { gate = 0; d = j; }
    Wt[(size_t)j * 512 + k] = f2b(W[((size_t)gate * 512 + k) * 512 + d]);
}

// ---------------- GEMM + fused gate epilogue (R12 loop verbatim) --------
// 8 waves (BM=256 x BN=128), 64x64 wave tile, BK=32, R7 chunk swizzle
// (0 conflicts), triple-buffer + counted vmcnt(3) depth-2, XCD swizzle.
// __launch_bounds__(512,4): natural VGPR 64, 2 blocks/CU = 16 waves/CU
// (the confirmed controlling variable; R13 lesson: do not force tighter).
// Gate-interleaved B columns (cvt_wt): lane's acc[m][n] = gate n of same d.
// MODE 1: writes f1 (sigm) -> o0, g1=(1-f1)*tanh(uv) -> o1   [2 streams]
// MODE 2: writes f2 -> o0, g=(1-f2)*sigm(ui)*tanh(uz) -> o1, o -> o2 [3]
// MODE 3: raw + bias -> o0 (f32)
template <int MODE>
__global__ __launch_bounds__(512, 4) void gemm_act(
    const u16* __restrict__ A, const u16* __restrict__ Bt,
    const float* __restrict__ bias, void* __restrict__ o0v,
    void* __restrict__ o1v, void* __restrict__ o2v) {
    constexpr int K = 512;
    constexpr int BK = 32;             // K-step (u16), 64B rows
    constexpr int NKT = K / BK;        // 16
    constexpr int LBA = 256 * 32;      // A: 16KB per buffer
    constexpr int LBB = 128 * 32;      // B: 8KB per buffer
    constexpr int GX = (MODE == 1) ? 8 : (MODE == 2) ? 16 : 4;
    constexpr int NWG = 128 * GX;
    __shared__ u16 lsA[3][LBA];        // 48KB
    __shared__ u16 lsB[3][LBB];        // 24KB
    const int tid = threadIdx.x;
    const int lane = tid & 63;
    const int wid = tid >> 6;          // 0..7
    const int wr = wid >> 1;           // 0..3 (M: 64-row quarter)
    const int wc = wid & 1;            // 0..1 (N: 64-col half)
    const int l0 = lane & 15, lh = lane >> 4;

    // chunked XCD swizzle (bijective: NWG % 8 == 0)
    const int h = blockIdx.x;
    const int l = (h & 7) * (NWG / 8) + (h >> 3);
    const int bn0 = (l & (GX - 1)) * 128;
    const int bm0 = (l / GX) * 256;

    float4v acc[4][4];
#pragma unroll
    for (int m = 0; m < 4; ++m)
#pragma unroll
        for (int n = 0; n < 4; ++n) acc[m][n] = (float4v){0.f, 0.f, 0.f, 0.f};

    // staging: A 2 instrs (1024 slots), B 1 instr (512 slots); 3 loads/thread
    int growA[2], gchA[2], growB, gchB;
#pragma unroll
    for (int i = 0; i < 2; ++i) {
        int flat = i * 512 + tid;
        growA[i] = flat >> 2;
        gchA[i] = (((flat & 3) ^ ((growA[i] >> 1) & 3))) * 8;
    }
    growB = tid >> 2;
    gchB = (((tid & 3) ^ ((growB >> 1) & 3))) * 8;

#define STAGE(buf, kt)                                                        \
    {                                                                         \
        const int k0 = (kt) * BK;                                             \
        _Pragma("unroll") for (int i = 0; i < 2; ++i)                         \
            gl2lds16(&A[(size_t)(bm0 + growA[i]) * K + k0 + gchA[i]],         \
                     &lsA[buf][(i * 512 + tid) * 8]);                         \
        gl2lds16(&Bt[(size_t)(bn0 + growB) * K + k0 + gchB],                  \
                 &lsB[buf][tid * 8]);                                         \
    }

    // prologue: 2 tiles in flight (6 loads/thread outstanding)
    STAGE(0, 0);
    STAGE(1, 1);

    for (int kt = 0; kt < NKT; ++kt) {
        const int cur = kt % 3;
        if (kt + 1 < NKT)
            asm volatile("s_waitcnt vmcnt(3)" ::: "memory");
        else
            asm volatile("s_waitcnt vmcnt(0)" ::: "memory");
        __builtin_amdgcn_s_barrier();
        __builtin_amdgcn_sched_barrier(0);
        if (kt + 2 < NKT) STAGE((kt + 2) % 3, kt + 2);
        short8 af[4], bf[4];
#pragma unroll
        for (int m = 0; m < 4; ++m) {
            int r = wr * 64 + m * 16 + l0;
            af[m] = *(const short8*)&lsA[cur][r * 32 + ((lh ^ ((r >> 1) & 3)) * 8)];
        }
#pragma unroll
        for (int n = 0; n < 4; ++n) {
            int r = wc * 64 + n * 16 + l0;
            bf[n] = *(const short8*)&lsB[cur][r * 32 + ((lh ^ ((r >> 1) & 3)) * 8)];
        }
        asm volatile("s_waitcnt lgkmcnt(0)" ::: "memory");
        __builtin_amdgcn_sched_barrier(0);
        __builtin_amdgcn_s_setprio(1);
#pragma unroll
        for (int m = 0; m < 4; ++m)
#pragma unroll
            for (int n = 0; n < 4; ++n)
                acc[m][n] = __builtin_amdgcn_mfma_f32_16x16x32_bf16(
                    af[m], bf[n], acc[m][n], 0, 0, 0);
        __builtin_amdgcn_s_setprio(0);
    }
#undef STAGE

    if (MODE == 3) {
#pragma unroll
        for (int m = 0; m < 4; ++m) {
#pragma unroll
            for (int n = 0; n < 4; ++n) {
                int col = bn0 + wc * 64 + n * 16 + l0;
                float bv = bias[col];
#pragma unroll
                for (int r = 0; r < 4; ++r) {
                    int rw = bm0 + wr * 64 + m * 16 + lh * 4 + r;
                    ((float*)o0v)[(size_t)rw * 512 + col] = acc[m][n][r] + bv;
                }
            }
        }
    } else if (MODE == 1) {
        // pairs (n=2p: v-gate, n=2p+1: f-gate) share d = (base5+p)*16+l0
        const int base5 = (bn0 + wc * 64) >> 5;
#pragma unroll
        for (int p = 0; p < 2; ++p) {
            const int d = (base5 + p) * 16 + l0;
            const float bvv = bias[d], bvf = bias[512 + d];
#pragma unroll
            for (int m = 0; m < 4; ++m) {
#pragma unroll
                for (int r = 0; r < 4; ++r) {
                    int rw = bm0 + wr * 64 + m * 16 + lh * 4 + r;
                    float f1 = sigm(acc[m][2 * p + 1][r] + bvf);
                    float g = (1.f - f1) * tanh_fast(acc[m][2 * p][r] + bvv);
                    size_t oidx = (size_t)rw * 512 + d;
                    ((u16*)o0v)[oidx] = f2b(f1);
                    ((u16*)o1v)[oidx] = f2b(g);
                }
            }
        }
    } else {  // MODE 2: acc[m][0..3] = f2,i,o,z of same d
        const int d = ((bn0 + wc * 64) >> 6) * 16 + l0;
        const float bv0 = bias[d], bv1 = bias[512 + d];
        const float bv2 = bias[1024 + d], bv3 = bias[1536 + d];
#pragma unroll
        for (int m = 0; m < 4; ++m) {
#pragma unroll
            for (int r = 0; r < 4; ++r) {
                int rw = bm0 + wr * 64 + m * 16 + lh * 4 + r;
                float f2 = sigm(acc[m][0][r] + bv0);
                float ii = sigm(acc[m][1][r] + bv1);
                float oo = sigm(acc[m][2][r] + bv2);
                float zz = tanh_fast(acc[m][3][r] + bv3);
                float g = (1.f - f2) * ii * zz;
                size_t oidx = (size_t)rw * 512 + d;
                ((u16*)o0v)[oidx] = f2b(f2);
                ((u16*)o1v)[oidx] = f2b(g);
                ((u16*)o2v)[oidx] = f2b(oo);
            }
        }
    }
}

// ---------------- chunked scan (f,g bf16 streams, f32 state) ------------
// h_t = f_t*h_{t-1} + g_t ; g precomputed in GEMM epilogue.
__global__ __launch_bounds__(128) void scan_p1(const u16* __restrict__ f,
                                               const u16* __restrict__ g,
                                               float* __restrict__ cA,
                                               float* __restrict__ cB) {
    int d0 = threadIdx.x * 4;
    int c = blockIdx.x & (NC - 1);
    int b = blockIdx.x >> 7;
    size_t base = ((size_t)b * T_LEN + c * CH) * DDIM + d0;
    float Aa[4] = {1.f, 1.f, 1.f, 1.f}, Bb[4] = {0.f, 0.f, 0.f, 0.f};
    for (int t = 0; t < CH; ++t) {
        ushort4 fq = *(const ushort4*)&f[base];
        ushort4 gq = *(const ushort4*)&g[base];
        float ff[4] = {b2f(fq.x), b2f(fq.y), b2f(fq.z), b2f(fq.w)};
        float gg[4] = {b2f(gq.x), b2f(gq.y), b2f(gq.z), b2f(gq.w)};
#pragma unroll
        for (int j = 0; j < 4; ++j) {
            Bb[j] = ff[j] * Bb[j] + gg[j];
            Aa[j] *= ff[j];
        }
        base += DDIM;
    }
    size_t ci = (size_t)c * 4096 + b * DDIM + d0;
#pragma unroll
    for (int j = 0; j < 4; ++j) {
        cA[ci + j] = Aa[j];
        cB[ci + j] = Bb[j];
    }
}

__global__ __launch_bounds__(256) void scan_p2(float* __restrict__ cA,
                                               const float* __restrict__ cB) {
    int ln = blockIdx.x * 256 + threadIdx.x;  // 0..4095 = b*512+d
    float h = 0.f;
    for (int c = 0; c < NC; ++c) {
        size_t ix = (size_t)c * 4096 + ln;
        float a = cA[ix], bb = cB[ix];
        cA[ix] = h;  // exclusive carry-in
        h = a * h + bb;
    }
}

template <int S>  // S==2: multiply by o before store; hid offset
__global__ __launch_bounds__(128) void scan_p3(
    const u16* __restrict__ f, const u16* __restrict__ g,
    const u16* __restrict__ o, const float* __restrict__ cA,
    u16* __restrict__ hb, float* __restrict__ hid) {
    int d0 = threadIdx.x * 4;
    int c = blockIdx.x & (NC - 1);
    int b = blockIdx.x >> 7;
    size_t base = ((size_t)b * T_LEN + c * CH) * DDIM + d0;
    size_t ci = (size_t)c * 4096 + b * DDIM + d0;
    float h[4] = {cA[ci], cA[ci + 1], cA[ci + 2], cA[ci + 3]};
    for (int t = 0; t < CH; ++t) {
        ushort4 fq = *(const ushort4*)&f[base];
        ushort4 gq = *(const ushort4*)&g[base];
        float ff[4] = {b2f(fq.x), b2f(fq.y), b2f(fq.z), b2f(fq.w)};
        float gg[4] = {b2f(gq.x), b2f(gq.y), b2f(gq.z), b2f(gq.w)};
        float w[4];
#pragma unroll
        for (int j = 0; j < 4; ++j) {
            h[j] = ff[j] * h[j] + gg[j];
            w[j] = h[j];
        }
        if (S == 2) {
            ushort4 oq = *(const ushort4*)&o[base];
            w[0] *= b2f(oq.x); w[1] *= b2f(oq.y);
            w[2] *= b2f(oq.z); w[3] *= b2f(oq.w);
        }
        ushort4 p;
        p.x = f2b(w[0]); p.y = f2b(w[1]); p.z = f2b(w[2]); p.w = f2b(w[3]);
        *(ushort4*)&hb[base] = p;
        base += DDIM;
    }
    if (c == NC - 1) {
#pragma unroll
        for (int j = 0; j < 4; ++j)
            hid[b * 1024 + (S == 1 ? 0 : 512) + d0 + j] = h[j];
    }
}

// ---------------- launch ----------------
extern "C" void kernel_launch(void* const* d_in, const int* in_sizes, int n_in,
                              void* d_out, int out_size, void* d_ws,
                              size_t ws_size, hipStream_t stream) {
    const float* x = (const float*)d_in[0];
    const float* W_in = (const float*)d_in[1];
    const float* b_in = (const float*)d_in[2];
    const float* W_mid = (const float*)d_in[3];
    const float* b_mid = (const float*)d_in[4];
    const float* W_out = (const float*)d_in[5];
    const float* b_out = (const float*)d_in[6];
    float* out = (float*)d_out;
    char* ws = (char*)d_ws;

    const size_t MB = 1u << 20;
    const size_t MD = (size_t)MROWS * DDIM;  // 16.7M elems

    u16* wt_in = (u16*)(ws);              // 1 MB
    u16* wt_mid = (u16*)(ws + 1 * MB);    // 2 MB
    u16* wt_out = (u16*)(ws + 3 * MB);    // 0.5 MB
    u16* hb = (u16*)(ws + 4 * MB);        // 32 MB (xb -> h1 -> s)
    u16* S0 = (u16*)(ws + 36 * MB);       // 32 MB (f stream)
    u16* S1 = (u16*)(ws + 68 * MB);       // 32 MB (g stream)
    u16* S2 = (u16*)(ws + 100 * MB);      // 32 MB (o stream)
    float* cA = (float*)(ws + 164 * MB);  // 2 MB
    float* cB = (float*)(ws + 166 * MB);  // 2 MB
    float* hid = out + MD;

    cvt_x<<<(int)(MD / 4 / 256), 256, 0, stream>>>(x, hb, MD);
    cvt_wt<1><<<(1024 * 512) / 256, 256, 0, stream>>>(W_in, wt_in, 1024);
    cvt_wt<2><<<(2048 * 512) / 256, 256, 0, stream>>>(W_mid, wt_mid, 2048);
    cvt_wt<3><<<(512 * 512) / 256, 256, 0, stream>>>(W_out, wt_out, 512);

    // GEMM1: f1(S0), g1(S1)   (128 Mblk x 8 Nblk = 1024)
    gemm_act<1><<<1024, 512, 0, stream>>>(hb, wt_in, b_in, S0, S1, nullptr);
    // scan1: h1 = scan(f1, g1) -> hb bf16; hidden_pre
    scan_p1<<<1024, 128, 0, stream>>>(S0, S1, cA, cB);
    scan_p2<<<16, 256, 0, stream>>>(cA, cB);
    scan_p3<1><<<1024, 128, 0, stream>>>(S0, S1, nullptr, cA, hb, hid);

    // GEMM2: f2(S0), g(S1), o(S2)  (128 x 16 = 2048)
    gemm_act<2><<<2048, 512, 0, stream>>>(hb, wt_mid, b_mid, S0, S1, S2);
    // scan2: h2 = scan(f2, g); s = h2*o -> hb bf16; hidden_middle
    scan_p1<<<1024, 128, 0, stream>>>(S0, S1, cA, cB);
    scan_p2<<<16, 256, 0, stream>>>(cA, cB);
    scan_p3<2><<<1024, 128, 0, stream>>>(S0, S1, S2, cA, hb, hid);

    // GEMM3: out = s@W_out + b_out (f32)  (128 x 4 = 512)
    gemm_act<3><<<512, 512, 0, stream>>>(hb, wt_out, b_out, out, nullptr,
                                         nullptr);
}

// Round 17
// 243.971 us; speedup vs baseline: 1.3954x; 1.0645x over previous
//
#include <hip/hip_runtime.h>

typedef short short8 __attribute__((ext_vector_type(8)));
typedef float float4v __attribute__((ext_vector_type(4)));
typedef unsigned short u16;
typedef unsigned int u32;

#define T_LEN 4096
#define DDIM 512
#define BATCH 8
#define MROWS 32768
#define CH 32
#define NC 128   // T_LEN / CH

__device__ __forceinline__ u16 f2b(float x) {
    unsigned u = __float_as_uint(x);
    unsigned r = (u + 0x7FFFu + ((u >> 16) & 1u)) >> 16;
    return (u16)r;
}
__device__ __forceinline__ float b2f(u16 h) {
    return __uint_as_float((u32)h << 16);
}
__device__ __forceinline__ float sigm(float x) {
    return __builtin_amdgcn_rcpf(1.f + __builtin_amdgcn_exp2f(-1.44269504f * x));
}
__device__ __forceinline__ float tanh_fast(float x) {
    return 1.f - 2.f * __builtin_amdgcn_rcpf(1.f + __builtin_amdgcn_exp2f(2.88539008f * x));
}

__device__ __forceinline__ void gl2lds16(const u16* g, u16* l) {
    __builtin_amdgcn_global_load_lds(
        (const __attribute__((address_space(1))) void*)g,
        (__attribute__((address_space(3))) void*)l, 16, 0, 0);
}

// ordered affine compose across lh lanes: (a,b) := hi ∘ lo,
// lo = lower-lh half, compose(lo,hi) = (a_hi*a_lo, a_hi*b_lo + b_hi)
__device__ __forceinline__ void compose_xor(float& A, float& B, int mask,
                                            bool selfIsHi) {
    float pa = __shfl_xor(A, mask);
    float pb = __shfl_xor(B, mask);
    float loA = selfIsHi ? pa : A, loB = selfIsHi ? pb : B;
    float hiA = selfIsHi ? A : pa, hiB = selfIsHi ? B : pb;
    A = hiA * loA;
    B = hiA * loB + hiB;
}

// ---------------- converts ----------------
__global__ __launch_bounds__(256) void cvt_x(const float* __restrict__ x,
                                             u16* __restrict__ xb, size_t n) {
    size_t i = ((size_t)blockIdx.x * 256 + threadIdx.x) * 4;
    if (i < n) {
        float4v v = *(const float4v*)&x[i];
        ushort4 p;
        p.x = f2b(v[0]); p.y = f2b(v[1]); p.z = f2b(v[2]); p.w = f2b(v[3]);
        *(ushort4*)&xb[i] = p;
    }
}

// Gate-interleaved weight transpose (see R16)
template <int MODE>
__global__ __launch_bounds__(256) void cvt_wt(const float* __restrict__ W,
                                              u16* __restrict__ Wt, int N) {
    int idx = blockIdx.x * 256 + threadIdx.x;
    if (idx >= N * 512) return;
    int j = idx >> 9;
    int k = idx & 511;
    int gate, d;
    if (MODE == 1) { gate = (j >> 4) & 1; d = (j >> 5) * 16 + (j & 15); }
    else if (MODE == 2) { gate = (j >> 4) & 3; d = (j >> 6) * 16 + (j & 15); }
    else { gate = 0; d = j; }
    Wt[(size_t)j * 512 + k] = f2b(W[((size_t)gate * 512 + k) * 512 + d]);
}

// ---------------- GEMM + fused gate epilogue + fused scan partials ------
// R12/R16 loop verbatim (8 waves, BM=256 x BN=128, 64x64 wave tile, BK=32,
// R7 chunk swizzle, triple-buffer counted vmcnt(3), XCD swizzle).
// NEW: epilogue also computes per-chunk scan partials (A = prod f,
// B = affine compose of (f,g)) in t-order -- the block's 256 rows are 256
// consecutive t within one batch = 8 chunks of 32. Order: r (in-thread),
// lh (2 ordered shfl_xor compose steps), m-pair (in-thread). Lane lh==0
// writes (A,B) to cA/cB. This replaces the scan_p1 kernel (f32-accurate,
// saves its 64MB re-read + launch).
// MODE 1: f1->o0, g1->o1 (bf16) + partials. MODE 2: f2->o0, g->o1, o->o2
// + partials. MODE 3: raw+bias f32, no partials.
template <int MODE>
__global__ __launch_bounds__(512, 4) void gemm_act(
    const u16* __restrict__ A, const u16* __restrict__ Bt,
    const float* __restrict__ bias, void* __restrict__ o0v,
    void* __restrict__ o1v, void* __restrict__ o2v,
    float* __restrict__ cA, float* __restrict__ cB) {
    constexpr int K = 512;
    constexpr int BK = 32;
    constexpr int NKT = K / BK;        // 16
    constexpr int LBA = 256 * 32;
    constexpr int LBB = 128 * 32;
    constexpr int GX = (MODE == 1) ? 8 : (MODE == 2) ? 16 : 4;
    constexpr int NWG = 128 * GX;
    __shared__ u16 lsA[3][LBA];        // 48KB
    __shared__ u16 lsB[3][LBB];        // 24KB
    const int tid = threadIdx.x;
    const int lane = tid & 63;
    const int wid = tid >> 6;
    const int wr = wid >> 1;           // 0..3 (M quarter)
    const int wc = wid & 1;            // 0..1 (N half)
    const int l0 = lane & 15, lh = lane >> 4;

    const int h = blockIdx.x;
    const int l = (h & 7) * (NWG / 8) + (h >> 3);
    const int bn0 = (l & (GX - 1)) * 128;
    const int bm0 = (l / GX) * 256;

    float4v acc[4][4];
#pragma unroll
    for (int m = 0; m < 4; ++m)
#pragma unroll
        for (int n = 0; n < 4; ++n) acc[m][n] = (float4v){0.f, 0.f, 0.f, 0.f};

    int growA[2], gchA[2], growB, gchB;
#pragma unroll
    for (int i = 0; i < 2; ++i) {
        int flat = i * 512 + tid;
        growA[i] = flat >> 2;
        gchA[i] = (((flat & 3) ^ ((growA[i] >> 1) & 3))) * 8;
    }
    growB = tid >> 2;
    gchB = (((tid & 3) ^ ((growB >> 1) & 3))) * 8;

#define STAGE(buf, kt)                                                        \
    {                                                                         \
        const int k0 = (kt) * BK;                                             \
        _Pragma("unroll") for (int i = 0; i < 2; ++i)                         \
            gl2lds16(&A[(size_t)(bm0 + growA[i]) * K + k0 + gchA[i]],         \
                     &lsA[buf][(i * 512 + tid) * 8]);                         \
        gl2lds16(&Bt[(size_t)(bn0 + growB) * K + k0 + gchB],                  \
                 &lsB[buf][tid * 8]);                                         \
    }

    STAGE(0, 0);
    STAGE(1, 1);

    for (int kt = 0; kt < NKT; ++kt) {
        const int cur = kt % 3;
        if (kt + 1 < NKT)
            asm volatile("s_waitcnt vmcnt(3)" ::: "memory");
        else
            asm volatile("s_waitcnt vmcnt(0)" ::: "memory");
        __builtin_amdgcn_s_barrier();
        __builtin_amdgcn_sched_barrier(0);
        if (kt + 2 < NKT) STAGE((kt + 2) % 3, kt + 2);
        short8 af[4], bf[4];
#pragma unroll
        for (int m = 0; m < 4; ++m) {
            int r = wr * 64 + m * 16 + l0;
            af[m] = *(const short8*)&lsA[cur][r * 32 + ((lh ^ ((r >> 1) & 3)) * 8)];
        }
#pragma unroll
        for (int n = 0; n < 4; ++n) {
            int r = wc * 64 + n * 16 + l0;
            bf[n] = *(const short8*)&lsB[cur][r * 32 + ((lh ^ ((r >> 1) & 3)) * 8)];
        }
        asm volatile("s_waitcnt lgkmcnt(0)" ::: "memory");
        __builtin_amdgcn_sched_barrier(0);
        __builtin_amdgcn_s_setprio(1);
#pragma unroll
        for (int m = 0; m < 4; ++m)
#pragma unroll
            for (int n = 0; n < 4; ++n)
                acc[m][n] = __builtin_amdgcn_mfma_f32_16x16x32_bf16(
                    af[m], bf[n], acc[m][n], 0, 0, 0);
        __builtin_amdgcn_s_setprio(0);
    }
#undef STAGE

    if (MODE == 3) {
#pragma unroll
        for (int m = 0; m < 4; ++m) {
#pragma unroll
            for (int n = 0; n < 4; ++n) {
                int col = bn0 + wc * 64 + n * 16 + l0;
                float bv = bias[col];
#pragma unroll
                for (int r = 0; r < 4; ++r) {
                    int rw = bm0 + wr * 64 + m * 16 + lh * 4 + r;
                    ((float*)o0v)[(size_t)rw * 512 + col] = acc[m][n][r] + bv;
                }
            }
        }
        return;
    }

    const int bb = bm0 >> 12;                 // batch index
    const int tq = (bm0 & 4095) + wr * 64;    // quarter's t-base (mult of 64)

    if (MODE == 1) {
        const int base5 = (bn0 + wc * 64) >> 5;
#pragma unroll
        for (int p = 0; p < 2; ++p) {
            const int d = (base5 + p) * 16 + l0;
            const float bvv = bias[d], bvf = bias[512 + d];
            float segA[4], segB[4];
#pragma unroll
            for (int m = 0; m < 4; ++m) {
                float Ap = 1.f, Bp = 0.f;
#pragma unroll
                for (int r = 0; r < 4; ++r) {
                    int rw = bm0 + wr * 64 + m * 16 + lh * 4 + r;
                    float f1 = sigm(acc[m][2 * p + 1][r] + bvf);
                    float g = (1.f - f1) * tanh_fast(acc[m][2 * p][r] + bvv);
                    size_t oidx = (size_t)rw * 512 + d;
                    ((u16*)o0v)[oidx] = f2b(f1);
                    ((u16*)o1v)[oidx] = f2b(g);
                    Bp = f1 * Bp + g;
                    Ap *= f1;
                }
                segA[m] = Ap; segB[m] = Bp;
            }
#pragma unroll
            for (int m = 0; m < 4; ++m) {
                compose_xor(segA[m], segB[m], 16, (lh & 1) != 0);
                compose_xor(segA[m], segB[m], 32, (lh & 2) != 0);
            }
            if (lh == 0) {
                float c0A = segA[1] * segA[0], c0B = segA[1] * segB[0] + segB[1];
                float c1A = segA[3] * segA[2], c1B = segA[3] * segB[2] + segB[3];
                int c0 = tq >> 5;
                size_t ci0 = (size_t)c0 * 4096 + bb * 512 + d;
                size_t ci1 = ci0 + 4096;
                cA[ci0] = c0A; cB[ci0] = c0B;
                cA[ci1] = c1A; cB[ci1] = c1B;
            }
        }
    } else {  // MODE 2: acc[m][0..3] = f2,i,o,z of same d
        const int d = ((bn0 + wc * 64) >> 6) * 16 + l0;
        const float bv0 = bias[d], bv1 = bias[512 + d];
        const float bv2 = bias[1024 + d], bv3 = bias[1536 + d];
        float segA[4], segB[4];
#pragma unroll
        for (int m = 0; m < 4; ++m) {
            float Ap = 1.f, Bp = 0.f;
#pragma unroll
            for (int r = 0; r < 4; ++r) {
                int rw = bm0 + wr * 64 + m * 16 + lh * 4 + r;
                float f2 = sigm(acc[m][0][r] + bv0);
                float ii = sigm(acc[m][1][r] + bv1);
                float oo = sigm(acc[m][2][r] + bv2);
                float zz = tanh_fast(acc[m][3][r] + bv3);
                float g = (1.f - f2) * ii * zz;
                size_t oidx = (size_t)rw * 512 + d;
                ((u16*)o0v)[oidx] = f2b(f2);
                ((u16*)o1v)[oidx] = f2b(g);
                ((u16*)o2v)[oidx] = f2b(oo);
                Bp = f2 * Bp + g;
                Ap *= f2;
            }
            segA[m] = Ap; segB[m] = Bp;
        }
#pragma unroll
        for (int m = 0; m < 4; ++m) {
            compose_xor(segA[m], segB[m], 16, (lh & 1) != 0);
            compose_xor(segA[m], segB[m], 32, (lh & 2) != 0);
        }
        if (lh == 0) {
            float c0A = segA[1] * segA[0], c0B = segA[1] * segB[0] + segB[1];
            float c1A = segA[3] * segA[2], c1B = segA[3] * segB[2] + segB[3];
            int c0 = tq >> 5;
            size_t ci0 = (size_t)c0 * 4096 + bb * 512 + d;
            size_t ci1 = ci0 + 4096;
            cA[ci0] = c0A; cB[ci0] = c0B;
            cA[ci1] = c1A; cB[ci1] = c1B;
        }
    }
}

// ---------------- scan pass 2 + 3 (p1 now fused into GEMM epilogue) -----
__global__ __launch_bounds__(256) void scan_p2(float* __restrict__ cA,
                                               const float* __restrict__ cB) {
    int ln = blockIdx.x * 256 + threadIdx.x;  // 0..4095 = b*512+d
    float h = 0.f;
    for (int c = 0; c < NC; ++c) {
        size_t ix = (size_t)c * 4096 + ln;
        float a = cA[ix], bb = cB[ix];
        cA[ix] = h;  // exclusive carry-in
        h = a * h + bb;
    }
}

template <int S>  // S==2: multiply by o before store; hid offset
__global__ __launch_bounds__(128) void scan_p3(
    const u16* __restrict__ f, const u16* __restrict__ g,
    const u16* __restrict__ o, const float* __restrict__ cA,
    u16* __restrict__ hb, float* __restrict__ hid) {
    int d0 = threadIdx.x * 4;
    int c = blockIdx.x & (NC - 1);
    int b = blockIdx.x >> 7;
    size_t base = ((size_t)b * T_LEN + c * CH) * DDIM + d0;
    size_t ci = (size_t)c * 4096 + b * DDIM + d0;
    float h[4] = {cA[ci], cA[ci + 1], cA[ci + 2], cA[ci + 3]};
    for (int t = 0; t < CH; ++t) {
        ushort4 fq = *(const ushort4*)&f[base];
        ushort4 gq = *(const ushort4*)&g[base];
        float ff[4] = {b2f(fq.x), b2f(fq.y), b2f(fq.z), b2f(fq.w)};
        float gg[4] = {b2f(gq.x), b2f(gq.y), b2f(gq.z), b2f(gq.w)};
        float w[4];
#pragma unroll
        for (int j = 0; j < 4; ++j) {
            h[j] = ff[j] * h[j] + gg[j];
            w[j] = h[j];
        }
        if (S == 2) {
            ushort4 oq = *(const ushort4*)&o[base];
            w[0] *= b2f(oq.x); w[1] *= b2f(oq.y);
            w[2] *= b2f(oq.z); w[3] *= b2f(oq.w);
        }
        ushort4 p;
        p.x = f2b(w[0]); p.y = f2b(w[1]); p.z = f2b(w[2]); p.w = f2b(w[3]);
        *(ushort4*)&hb[base] = p;
        base += DDIM;
    }
    if (c == NC - 1) {
#pragma unroll
        for (int j = 0; j < 4; ++j)
            hid[b * 1024 + (S == 1 ? 0 : 512) + d0 + j] = h[j];
    }
}

// ---------------- launch ----------------
extern "C" void kernel_launch(void* const* d_in, const int* in_sizes, int n_in,
                              void* d_out, int out_size, void* d_ws,
                              size_t ws_size, hipStream_t stream) {
    const float* x = (const float*)d_in[0];
    const float* W_in = (const float*)d_in[1];
    const float* b_in = (const float*)d_in[2];
    const float* W_mid = (const float*)d_in[3];
    const float* b_mid = (const float*)d_in[4];
    const float* W_out = (const float*)d_in[5];
    const float* b_out = (const float*)d_in[6];
    float* out = (float*)d_out;
    char* ws = (char*)d_ws;

    const size_t MB = 1u << 20;
    const size_t MD = (size_t)MROWS * DDIM;  // 16.7M elems

    u16* wt_in = (u16*)(ws);              // 1 MB
    u16* wt_mid = (u16*)(ws + 1 * MB);    // 2 MB
    u16* wt_out = (u16*)(ws + 3 * MB);    // 0.5 MB
    u16* hb = (u16*)(ws + 4 * MB);        // 32 MB (xb -> h1 -> s)
    u16* S0 = (u16*)(ws + 36 * MB);       // 32 MB (f stream)
    u16* S1 = (u16*)(ws + 68 * MB);       // 32 MB (g stream)
    u16* S2 = (u16*)(ws + 100 * MB);      // 32 MB (o stream)
    float* cA = (float*)(ws + 164 * MB);  // 2 MB
    float* cB = (float*)(ws + 166 * MB);  // 2 MB
    float* hid = out + MD;

    cvt_x<<<(int)(MD / 4 / 256), 256, 0, stream>>>(x, hb, MD);
    cvt_wt<1><<<(1024 * 512) / 256, 256, 0, stream>>>(W_in, wt_in, 1024);
    cvt_wt<2><<<(2048 * 512) / 256, 256, 0, stream>>>(W_mid, wt_mid, 2048);
    cvt_wt<3><<<(512 * 512) / 256, 256, 0, stream>>>(W_out, wt_out, 512);

    // GEMM1: f1(S0), g1(S1) + chunk partials (128 Mblk x 8 Nblk = 1024)
    gemm_act<1><<<1024, 512, 0, stream>>>(hb, wt_in, b_in, S0, S1, nullptr,
                                          cA, cB);
    // scan1: carries, then h1 -> hb bf16; hidden_pre
    scan_p2<<<16, 256, 0, stream>>>(cA, cB);
    scan_p3<1><<<1024, 128, 0, stream>>>(S0, S1, nullptr, cA, hb, hid);

    // GEMM2: f2(S0), g(S1), o(S2) + chunk partials (128 x 16 = 2048)
    gemm_act<2><<<2048, 512, 0, stream>>>(hb, wt_mid, b_mid, S0, S1, S2,
                                          cA, cB);
    // scan2: carries, then h2*o -> hb bf16; hidden_middle
    scan_p2<<<16, 256, 0, stream>>>(cA, cB);
    scan_p3<2><<<1024, 128, 0, stream>>>(S0, S1, S2, cA, hb, hid);

    // GEMM3: out = s@W_out + b_out (f32)  (128 x 4 = 512)
    gemm_act<3><<<512, 512, 0, stream>>>(hb, wt_out, b_out, out, nullptr,
                                         nullptr, nullptr, nullptr);
}